// Round 5
// baseline (427.244 us; speedup 1.0000x reference)
//
#include <hip/hip_runtime.h>
#include <hip/hip_bf16.h>

#define BS 64
#define SL 50
#define SW 64
#define DIM 128
#define VOC 100000
#define VT 6250              // vocab tiles of 16
#define K4_BLOCKS 1563       // ceil(6250/4)

typedef __attribute__((ext_vector_type(8))) short short8;
typedef __attribute__((ext_vector_type(4))) float float4v;

// f32 -> bf16 bits, round-to-nearest-even (pure integer ops)
__device__ __forceinline__ short f2b(float f){
    unsigned int u = __float_as_uint(f);
    u += 0x7fffu + ((u >> 16) & 1u);
    return (short)(u >> 16);
}

// ---- K1: per-sentence gathered sums -> m[h][b][s][d], c[h][b][s][d] (f32) ----
// m_h = sum_w A[h][x_w]*pe_w + TA[s],  c_h = sum_w A[h+1][x_w] + TC[s].
// One pass: table t contributes to aPE[t] (t<3) and aPL[t-1] (t>0) from a
// single load.
__global__ __launch_bounds__(256) void k_gather(const int* __restrict__ x,
    const float* __restrict__ A, const float* __restrict__ TA,
    const float* __restrict__ TC, float* __restrict__ m, float* __restrict__ c)
{
    int s = blockIdx.x, b = blockIdx.y;
    int tid = threadIdx.x;
    int wv = tid >> 6, l = tid & 63;
    const int* xp = x + (b * SL + s) * SW;
    const float2* A2 = (const float2*)A;       // one row = 64 float2
    float aPE[3][2] = {{0.f,0.f},{0.f,0.f},{0.f,0.f}};
    float aPL[3][2] = {{0.f,0.f},{0.f,0.f},{0.f,0.f}};
    float kk0 = (2*l + 1) * (1.0f / DIM);
    float kk1 = (2*l + 2) * (1.0f / DIM);
    for (int wi = 0; wi < 16; ++wi) {
        int word = wv * 16 + wi;
        int idx  = xp[word];
        float j    = (word + 1) * (1.0f / SW);
        float om   = 1.0f - 2.0f * j;
        float base = 1.0f - j;
        float pe0 = base - kk0 * om, pe1 = base - kk1 * om;
        size_t roff = (size_t)idx * 64 + l;
        #pragma unroll
        for (int t = 0; t < 4; ++t) {
            float2 v = A2[(size_t)t * VOC * 64 + roff];
            if (t < 3) { aPE[t][0] += v.x * pe0; aPE[t][1] += v.y * pe1; }
            if (t > 0) { aPL[t-1][0] += v.x;     aPL[t-1][1] += v.y;     }
        }
    }
    __shared__ float red[4][6][DIM];
    #pragma unroll
    for (int t = 0; t < 3; ++t) {
        red[wv][t  ][2*l] = aPE[t][0]; red[wv][t  ][2*l+1] = aPE[t][1];
        red[wv][3+t][2*l] = aPL[t][0]; red[wv][3+t][2*l+1] = aPL[t][1];
    }
    __syncthreads();
    if (tid < DIM) {
        int d = tid;
        float ta = TA[s * DIM + d];
        float tc = TC[s * DIM + d];
        #pragma unroll
        for (int t = 0; t < 3; ++t) {
            float spe = red[0][t][d] + red[1][t][d] + red[2][t][d] + red[3][t][d];
            float spl = red[0][3+t][d] + red[1][3+t][d] + red[2][3+t][d] + red[3][3+t][d];
            size_t o = (((size_t)t * BS + b) * SL + s) * DIM + d;
            m[o] = spe + ta;
            c[o] = spl + tc;
        }
    }
}

// ---- K2: u[b][d] = sum_t A[0][q[b][t]][d] ----
__global__ void k_query(const int* __restrict__ q, const float* __restrict__ A,
                        float* __restrict__ u)
{
    int b = blockIdx.x, l = threadIdx.x;   // 64 threads
    const float2* A2 = (const float2*)A;
    float a0 = 0.f, a1 = 0.f;
    for (int t = 0; t < 16; ++t) {
        int idx = q[b * 16 + t];
        float2 v = A2[(size_t)idx * 64 + l];
        a0 += v.x; a1 += v.y;
    }
    u[b * DIM + 2*l]     = a0;
    u[b * DIM + 2*l + 1] = a1;
}

// ---- K3: one hop: p = softmax(m.u), u += p.c ----
__global__ void k_hop(const float* __restrict__ mh, const float* __restrict__ ch,
                      float* __restrict__ u)
{
    int b = blockIdx.x, l = threadIdx.x;   // 64 threads
    float u0 = u[b * DIM + 2*l], u1 = u[b * DIM + 2*l + 1];
    __shared__ float sc[SL];
    const float2* mb = (const float2*)(mh + (size_t)b * SL * DIM);
    for (int s = 0; s < SL; ++s) {
        float2 w = mb[s * 64 + l];
        float p = w.x * u0 + w.y * u1;
        for (int off = 32; off; off >>= 1) p += __shfl_down(p, off);
        if (l == 0) sc[s] = p;
    }
    __syncthreads();
    float mx = -1e30f;
    for (int s = 0; s < SL; ++s) mx = fmaxf(mx, sc[s]);
    float sum = 0.f;
    for (int s = 0; s < SL; ++s) sum += __expf(sc[s] - mx);
    float inv = 1.0f / sum;
    const float2* cb = (const float2*)(ch + (size_t)b * SL * DIM);
    float a0 = u0, a1 = u1;
    for (int s = 0; s < SL; ++s) {
        float p = __expf(sc[s] - mx) * inv;
        float2 w = cb[s * 64 + l];
        a0 += p * w.x;
        a1 += p * w.y;
    }
    u[b * DIM + 2*l]     = a0;
    u[b * DIM + 2*l + 1] = a1;
}

// ---- K_cast: u fp32 -> bf16 bits for MFMA A-fragments ----
__global__ void k_cast(const float* __restrict__ u, short* __restrict__ u16)
{
    int i = blockIdx.x * 256 + threadIdx.x;
    if (i < BS * DIM) u16[i] = f2b(u[i]);
}

// ---- K4: logits = u @ A3^T via bf16 MFMA (A3 converted on the fly); f32 out ----
__global__ __launch_bounds__(256) void k_logits(const float* __restrict__ A3,
    const short* __restrict__ u16, float* __restrict__ out)
{
    int tid = threadIdx.x;
    int wv = tid >> 6, lane = tid & 63;
    int n = lane & 15, qd = lane >> 4;
    int tile = blockIdx.x * 4 + wv;
    if (tile >= VT) return;           // no __syncthreads in this kernel
    short8 bfr[4];
    size_t brow = ((size_t)(tile * 16 + n)) * DIM + qd * 8;
    #pragma unroll
    for (int k = 0; k < 4; ++k) {
        const float* p = A3 + brow + (size_t)k * 32;
        float4v f0 = *(const float4v*)p;
        float4v f1 = *(const float4v*)(p + 4);
        bfr[k] = (short8){ f2b(f0.x), f2b(f0.y), f2b(f0.z), f2b(f0.w),
                           f2b(f1.x), f2b(f1.y), f2b(f1.z), f2b(f1.w) };
    }
    float4v acc[4];
    #pragma unroll
    for (int bt = 0; bt < 4; ++bt) {
        acc[bt] = (float4v){0.f, 0.f, 0.f, 0.f};
        size_t arow = ((size_t)(bt * 16 + n)) * DIM + qd * 8;
        #pragma unroll
        for (int k = 0; k < 4; ++k) {
            short8 af = *(const short8*)(u16 + arow + (size_t)k * 32);
            acc[bt] = __builtin_amdgcn_mfma_f32_16x16x32_bf16(af, bfr[k], acc[bt], 0, 0, 0);
        }
    }
    int v = tile * 16 + n;
    #pragma unroll
    for (int bt = 0; bt < 4; ++bt) {
        #pragma unroll
        for (int r = 0; r < 4; ++r) {
            int b = bt * 16 + qd * 4 + r;   // C/D: col=lane&15 (vocab), row=quad*4+reg (batch)
            out[(size_t)b * VOC + v] = acc[bt][r];
        }
    }
}

// ---- K5: part[b][j] = sum over slice j of exp(logit[b][v]); 8 slices/row ----
// logits <= ~9.5 so exp never overflows f32; no max pass needed.
__global__ void k_lsepart(const float* __restrict__ out, float* __restrict__ part)
{
    int j = blockIdx.x, b = blockIdx.y;
    int tid = threadIdx.x;   // 256
    const float4v* row = (const float4v*)(out + (size_t)b * VOC);  // 25000 float4
    float s = 0.f;
    int lo = j * 3125, hi = lo + 3125;
    for (int i = lo + tid; i < hi; i += 256) {
        float4v v = row[i];
        s += __expf(v.x) + __expf(v.y) + __expf(v.z) + __expf(v.w);
    }
    __shared__ float red[256];
    red[tid] = s;
    __syncthreads();
    for (int off = 128; off; off >>= 1) {
        if (tid < off) red[tid] += red[tid + off];
        __syncthreads();
    }
    if (tid == 0) part[b * 8 + j] = red[0];
}

// ---- K6: out[b][v] -= log(sum_j part[b][j]) ----
__global__ void k_sub(float* __restrict__ out, const float* __restrict__ part)
{
    int b = blockIdx.y;
    int i = blockIdx.x * 256 + threadIdx.x;   // float4 index
    float s = 0.f;
    #pragma unroll
    for (int j = 0; j < 8; ++j) s += part[b * 8 + j];
    float l = logf(s);
    if (i < VOC / 4) {
        float4v* p = (float4v*)(out + (size_t)b * VOC) + i;
        float4v t = *p;
        t.x -= l; t.y -= l; t.z -= l; t.w -= l;
        *p = t;
    }
}

extern "C" void kernel_launch(void* const* d_in, const int* in_sizes, int n_in,
                              void* d_out, int out_size, void* d_ws, size_t ws_size,
                              hipStream_t stream)
{
    const int*   x  = (const int*)d_in[0];
    const int*   q  = (const int*)d_in[1];
    const float* A  = (const float*)d_in[2];
    const float* TA = (const float*)d_in[3];
    const float* TC = (const float*)d_in[4];
    float* out = (float*)d_out;

    // ws use < 52 KB. Big m/c scratch lives inside d_out (6.4M f32 elems):
    // 2*1,228,800 f32 at out+0; dead before k_logits overwrites all of d_out.
    char*  ws   = (char*)d_ws;
    float* u    = (float*)ws;              // 64*128*4 = 32768 B
    short* u16  = (short*)(ws + 32768);    // 64*128*2 = 16384 B (16B-aligned)
    float* part = (float*)(ws + 49152);    // 64*8*4   = 2048 B

    float* m = out;
    float* c = m + (size_t)3 * BS * SL * DIM;   // end = 2,457,600 < 6,400,000

    k_gather<<<dim3(SL, BS), 256, 0, stream>>>(x, A, TA, TC, m, c);
    k_query<<<BS, 64, 0, stream>>>(q, A, u);
    for (int h = 0; h < 3; ++h)
        k_hop<<<BS, 64, 0, stream>>>(m + (size_t)h * BS * SL * DIM,
                                     c + (size_t)h * BS * SL * DIM, u);
    k_cast<<<(BS * DIM + 255) / 256, 256, 0, stream>>>(u, u16);
    k_logits<<<K4_BLOCKS, 256, 0, stream>>>(A + (size_t)3 * VOC * DIM, u16, out);
    k_lsepart<<<dim3(8, BS), 256, 0, stream>>>(out, part);
    k_sub<<<dim3((VOC / 4 + 255) / 256, BS), 256, 0, stream>>>(out, part);
}

// Round 6
// 408.932 us; speedup vs baseline: 1.0448x; 1.0448x over previous
//
#include <hip/hip_runtime.h>
#include <hip/hip_bf16.h>

#define BS 64
#define SL 50
#define SW 64
#define DIM 128
#define VOC 100000
#define VT 6250              // vocab tiles of 16
#define K4_BLOCKS 1563       // ceil(6250/4)

typedef __attribute__((ext_vector_type(8))) short short8;
typedef __attribute__((ext_vector_type(4))) float float4v;

// f32 -> bf16 bits, round-to-nearest-even (pure integer ops)
__device__ __forceinline__ short f2b(float f){
    unsigned int u = __float_as_uint(f);
    u += 0x7fffu + ((u >> 16) & 1u);
    return (short)(u >> 16);
}

// ---- K1: per-sentence gathered sums -> m[h][b][s][d], c[h][b][s][d] (f32) ----
// All 64 word-indices preloaded by one coalesced load; per-iteration index via
// __shfl (wave-uniform src lane) => 64 independent table loads per wave, no
// dependent-load chain.
__global__ __launch_bounds__(256) void k_gather(const int* __restrict__ x,
    const float* __restrict__ A, const float* __restrict__ TA,
    const float* __restrict__ TC, float* __restrict__ m, float* __restrict__ c)
{
    int s = blockIdx.x, b = blockIdx.y;
    int tid = threadIdx.x;
    int wv = tid >> 6, l = tid & 63;
    const int* xp = x + (b * SL + s) * SW;
    int myidx = xp[l];                         // whole sentence in one load
    const float2* A2 = (const float2*)A;       // one row = 64 float2
    float aPE[3][2] = {{0.f,0.f},{0.f,0.f},{0.f,0.f}};
    float aPL[3][2] = {{0.f,0.f},{0.f,0.f},{0.f,0.f}};
    float kk0 = (2*l + 1) * (1.0f / DIM);
    float kk1 = (2*l + 2) * (1.0f / DIM);
    #pragma unroll
    for (int wi = 0; wi < 16; ++wi) {
        int word = wv * 16 + wi;
        int idx  = __shfl(myidx, word);
        float j    = (word + 1) * (1.0f / SW);
        float om   = 1.0f - 2.0f * j;
        float base = 1.0f - j;
        float pe0 = base - kk0 * om, pe1 = base - kk1 * om;
        size_t roff = (size_t)idx * 64 + l;
        #pragma unroll
        for (int t = 0; t < 4; ++t) {
            float2 v = A2[(size_t)t * VOC * 64 + roff];
            if (t < 3) { aPE[t][0] += v.x * pe0; aPE[t][1] += v.y * pe1; }
            if (t > 0) { aPL[t-1][0] += v.x;     aPL[t-1][1] += v.y;     }
        }
    }
    __shared__ float red[4][6][DIM];
    #pragma unroll
    for (int t = 0; t < 3; ++t) {
        red[wv][t  ][2*l] = aPE[t][0]; red[wv][t  ][2*l+1] = aPE[t][1];
        red[wv][3+t][2*l] = aPL[t][0]; red[wv][3+t][2*l+1] = aPL[t][1];
    }
    __syncthreads();
    if (tid < DIM) {
        int d = tid;
        float ta = TA[s * DIM + d];
        float tc = TC[s * DIM + d];
        #pragma unroll
        for (int t = 0; t < 3; ++t) {
            float spe = red[0][t][d] + red[1][t][d] + red[2][t][d] + red[3][t][d];
            float spl = red[0][3+t][d] + red[1][3+t][d] + red[2][3+t][d] + red[3][3+t][d];
            size_t o = (((size_t)t * BS + b) * SL + s) * DIM + d;
            m[o] = spe + ta;
            c[o] = spl + tc;
        }
    }
}

// ---- K2: u = A[0][q].sum ; 3x (p=softmax(m.u), u+=p.c) ; emit u16 bf16 bits ----
__global__ void k_hops(const int* __restrict__ q, const float* __restrict__ A,
                       const float* __restrict__ m, const float* __restrict__ c,
                       short* __restrict__ u16)
{
    int b = blockIdx.x, l = threadIdx.x;   // 64 threads, one wave
    const float2* A2 = (const float2*)A;
    float u0 = 0.f, u1 = 0.f;
    for (int t = 0; t < 16; ++t) {
        int idx = q[b * 16 + t];
        float2 v = A2[(size_t)idx * 64 + l];
        u0 += v.x; u1 += v.y;
    }
    __shared__ float sc[SL];
    for (int h = 0; h < 3; ++h) {
        const float2* mb = (const float2*)(m + ((size_t)h * BS + b) * SL * DIM);
        const float2* cb = (const float2*)(c + ((size_t)h * BS + b) * SL * DIM);
        for (int s = 0; s < SL; ++s) {
            float2 w = mb[s * 64 + l];
            float p = w.x * u0 + w.y * u1;
            for (int off = 32; off; off >>= 1) p += __shfl_down(p, off);
            if (l == 0) sc[s] = p;
        }
        __syncthreads();
        float mx = -1e30f;
        for (int s = 0; s < SL; ++s) mx = fmaxf(mx, sc[s]);
        float sum = 0.f;
        for (int s = 0; s < SL; ++s) sum += __expf(sc[s] - mx);
        float inv = 1.0f / sum;
        float a0 = u0, a1 = u1;
        for (int s = 0; s < SL; ++s) {
            float p = __expf(sc[s] - mx) * inv;
            float2 w = cb[s * 64 + l];
            a0 += p * w.x;
            a1 += p * w.y;
        }
        u0 = a0; u1 = a1;
        __syncthreads();
    }
    u16[b * DIM + 2*l]     = f2b(u0);
    u16[b * DIM + 2*l + 1] = f2b(u1);
}

// ---- K3: logits = u @ A3^T via bf16 MFMA; f32 out; per-block expsum partials ----
__global__ __launch_bounds__(256) void k_logits(const float* __restrict__ A3,
    const short* __restrict__ u16g, float* __restrict__ out, float* __restrict__ part)
{
    __shared__ short su[BS * DIM];     // 16 KB staged A-operand
    __shared__ float lpart[4][64];
    int tid = threadIdx.x;
    const int* ug = (const int*)u16g;
    int* us = (int*)su;
    #pragma unroll
    for (int i = 0; i < 16; ++i) us[tid + 256 * i] = ug[tid + 256 * i];
    int wv = tid >> 6, lane = tid & 63;
    lpart[wv][lane] = 0.0f;
    __syncthreads();
    int n = lane & 15, qd = lane >> 4;
    int tile = blockIdx.x * 4 + wv;
    if (tile < VT) {
        short8 bfr[4];
        size_t brow = ((size_t)(tile * 16 + n)) * DIM + qd * 8;
        #pragma unroll
        for (int k = 0; k < 4; ++k) {
            const float* p = A3 + brow + (size_t)k * 32;
            float4v f0 = *(const float4v*)p;
            float4v f1 = *(const float4v*)(p + 4);
            bfr[k] = (short8){ f2b(f0.x), f2b(f0.y), f2b(f0.z), f2b(f0.w),
                               f2b(f1.x), f2b(f1.y), f2b(f1.z), f2b(f1.w) };
        }
        float4v acc[4];
        #pragma unroll
        for (int bt = 0; bt < 4; ++bt) {
            acc[bt] = (float4v){0.f, 0.f, 0.f, 0.f};
            int arow = (bt * 16 + n) * DIM + qd * 8;
            #pragma unroll
            for (int k = 0; k < 4; ++k) {
                short8 af = *(const short8*)(su + arow + k * 32);
                acc[bt] = __builtin_amdgcn_mfma_f32_16x16x32_bf16(af, bfr[k], acc[bt], 0, 0, 0);
            }
        }
        int v = tile * 16 + n;
        #pragma unroll
        for (int bt = 0; bt < 4; ++bt) {
            #pragma unroll
            for (int r = 0; r < 4; ++r) {
                int b = bt * 16 + qd * 4 + r;   // C/D: col=lane&15 (vocab), row=quad*4+reg (batch)
                float val = acc[bt][r];
                out[(size_t)b * VOC + v] = val;
                float e = __expf(val);
                e += __shfl_xor(e, 1);          // reduce across n within qd-group
                e += __shfl_xor(e, 2);
                e += __shfl_xor(e, 4);
                e += __shfl_xor(e, 8);
                if (n == 0) lpart[wv][b] = e;
            }
        }
    }
    __syncthreads();
    if (tid < 64)
        part[(size_t)blockIdx.x * 64 + tid] =
            lpart[0][tid] + lpart[1][tid] + lpart[2][tid] + lpart[3][tid];
}

// ---- K4: lse[b] = log(sum_blocks part) ----
__global__ void k_lse(const float* __restrict__ part, float* __restrict__ lse)
{
    int b = blockIdx.x, tid = threadIdx.x;   // 256 threads
    float s = 0.f;
    for (int i = tid; i < K4_BLOCKS; i += 256) s += part[(size_t)i * 64 + b];
    __shared__ float red[256];
    red[tid] = s;
    __syncthreads();
    for (int off = 128; off; off >>= 1) {
        if (tid < off) red[tid] += red[tid + off];
        __syncthreads();
    }
    if (tid == 0) lse[b] = logf(red[0]);
}

// ---- K5: out[b][v] -= lse[b] ----
__global__ void k_sub(float* __restrict__ out, const float* __restrict__ lse)
{
    int b = blockIdx.y;
    int i = blockIdx.x * 256 + threadIdx.x;   // float4 index
    float l = lse[b];
    if (i < VOC / 4) {
        float4v* p = (float4v*)(out + (size_t)b * VOC) + i;
        float4v t = *p;
        t.x -= l; t.y -= l; t.z -= l; t.w -= l;
        *p = t;
    }
}

extern "C" void kernel_launch(void* const* d_in, const int* in_sizes, int n_in,
                              void* d_out, int out_size, void* d_ws, size_t ws_size,
                              hipStream_t stream)
{
    const int*   x  = (const int*)d_in[0];
    const int*   q  = (const int*)d_in[1];
    const float* A  = (const float*)d_in[2];
    const float* TA = (const float*)d_in[3];
    const float* TC = (const float*)d_in[4];
    float* out = (float*)d_out;

    // ws use < 420 KB. Big m/c scratch lives inside d_out (6.4M f32 elems):
    // 2*1,228,800 f32 at out+0; dead before k_logits overwrites all of d_out.
    char*  ws   = (char*)d_ws;
    short* u16  = (short*)ws;              // 64*128*2 = 16384 B
    float* part = (float*)(ws + 16384);    // 1563*64*4 = 400128 B
    float* lse  = (float*)(ws + 16384 + 400128);   // 256 B

    float* m = out;
    float* c = m + (size_t)3 * BS * SL * DIM;   // end = 2,457,600 < 6,400,000

    k_gather<<<dim3(SL, BS), 256, 0, stream>>>(x, A, TA, TC, m, c);
    k_hops<<<BS, 64, 0, stream>>>(q, A, m, c, u16);
    k_logits<<<K4_BLOCKS, 256, 0, stream>>>(A + (size_t)3 * VOC * DIM, u16, out, part);
    k_lse<<<BS, 256, 0, stream>>>(part, lse);
    k_sub<<<dim3((VOC / 4 + 255) / 256, BS), 256, 0, stream>>>(out, lse);
}